// Round 2
// baseline (354.685 us; speedup 1.0000x reference)
//
#include <hip/hip_runtime.h>

#define BB 4
#define AA 512
#define DD 729
#define HH 512
#define WW 512

__global__ __launch_bounds__(256) void bp_kernel(
    const float* __restrict__ sino,
    const float* __restrict__ vol_origin,
    const float* __restrict__ det_origin,
    const float* __restrict__ vol_spacing,
    const float* __restrict__ det_spacing,
    const float* __restrict__ angles,
    float* __restrict__ out)
{
    // (cos, sin) per angle, pre-scaled by 1/det_spacing. Packed float2 so the
    // hot loop does one ds_read_b64 (broadcast, conflict-free).
    __shared__ float2 s_cs[AA];

    const int tid = threadIdx.y * 16 + threadIdx.x;
    const float inv_ds = 1.0f / det_spacing[0];

    for (int a = tid; a < AA; a += 256) {
        float th = angles[a];
        s_cs[a] = make_float2(cosf(th) * inv_ds, sinf(th) * inv_ds);
    }
    __syncthreads();

    // Each thread computes 4 pixels along x, strided by 16 (block tile 64x16).
    const int ix0 = blockIdx.x * 64 + threadIdx.x;
    const int iy  = blockIdx.y * 16 + threadIdx.y;
    const int b   = blockIdx.z;

    const float vsx = vol_spacing[1];
    const float xw0 = vol_origin[1] + (float)ix0 * vsx;
    const float yw  = vol_origin[0] + (float)iy * vol_spacing[0];
    const float off = -det_origin[0] * inv_ds;
    const float step_scale = 16.0f * vsx;   // u-step between the 4 pixels

    const float* __restrict__ srow = sino + (size_t)b * (AA * DD);

    float acc0 = 0.f, acc1 = 0.f, acc2 = 0.f, acc3 = 0.f;

    #pragma unroll 4
    for (int a = 0; a < AA; ++a) {
        const float2 cs = s_cs[a];
        // u for pixel 0; pixels 1..3 are +k*step (incremental, 1 add each).
        const float ub = fmaf(xw0, cs.x, fmaf(yw, cs.y, off));
        const float st = cs.x * step_scale;
        const float u0 = ub;
        const float u1 = u0 + st;
        const float u2 = u1 + st;
        const float u3 = u2 + st;

        // u is always in (0, DD-1) for this problem's geometry (|s| <= 362,
        // off = 364), so trunc==floor and both taps are in-bounds. The clamp
        // to [0, DD-2] is memory-safety only; it never triggers here.
        {
            int   i  = (int)u0;
            i        = min(max(i, 0), DD - 2);
            float fr = u0 - (float)i;
            float v0 = srow[i];
            float v1 = srow[i + 1];
            acc0 = fmaf(fr, v1 - v0, acc0 + v0);
        }
        {
            int   i  = (int)u1;
            i        = min(max(i, 0), DD - 2);
            float fr = u1 - (float)i;
            float v0 = srow[i];
            float v1 = srow[i + 1];
            acc1 = fmaf(fr, v1 - v0, acc1 + v0);
        }
        {
            int   i  = (int)u2;
            i        = min(max(i, 0), DD - 2);
            float fr = u2 - (float)i;
            float v0 = srow[i];
            float v1 = srow[i + 1];
            acc2 = fmaf(fr, v1 - v0, acc2 + v0);
        }
        {
            int   i  = (int)u3;
            i        = min(max(i, 0), DD - 2);
            float fr = u3 - (float)i;
            float v0 = srow[i];
            float v1 = srow[i + 1];
            acc3 = fmaf(fr, v1 - v0, acc3 + v0);
        }
        srow += DD;
    }

    const size_t o = ((size_t)b * HH + iy) * WW + ix0;
    out[o]      = acc0;
    out[o + 16] = acc1;
    out[o + 32] = acc2;
    out[o + 48] = acc3;
}

extern "C" void kernel_launch(void* const* d_in, const int* in_sizes, int n_in,
                              void* d_out, int out_size, void* d_ws, size_t ws_size,
                              hipStream_t stream) {
    const float* sino        = (const float*)d_in[0];
    // d_in[1] = volume_shape (int64) — compile-time constants HH/WW used.
    const float* vol_origin  = (const float*)d_in[2];
    const float* det_origin  = (const float*)d_in[3];
    const float* vol_spacing = (const float*)d_in[4];
    const float* det_spacing = (const float*)d_in[5];
    const float* angles      = (const float*)d_in[6];
    float* out = (float*)d_out;

    dim3 block(16, 16, 1);
    dim3 grid(WW / 64, HH / 16, BB);
    bp_kernel<<<grid, block, 0, stream>>>(sino, vol_origin, det_origin,
                                          vol_spacing, det_spacing, angles, out);
}

// Round 3
// 300.713 us; speedup vs baseline: 1.1795x; 1.1795x over previous
//
#include <hip/hip_runtime.h>

#define BB 4
#define AA 512
#define DD 729
#define HH 512
#define WW 512

// Coarsening = 2 pixels/thread: total waves = B*H*W/2/64 = 8192 = 32 waves/CU
// (full occupancy cap). x4 coarsening halved wave count to 16/CU and made the
// kernel latency-bound (R2: VALUBusy 45%, Occupancy 46%).
__global__ __launch_bounds__(256) void bp_kernel(
    const float* __restrict__ sino,
    const float* __restrict__ vol_origin,
    const float* __restrict__ det_origin,
    const float* __restrict__ vol_spacing,
    const float* __restrict__ det_spacing,
    const float* __restrict__ angles,
    float* __restrict__ out)
{
    // (cos,sin)/det_spacing per angle; single ds_read_b64 broadcast per angle.
    __shared__ float2 s_cs[AA];

    const int tid = threadIdx.y * 16 + threadIdx.x;
    const float inv_ds = 1.0f / det_spacing[0];

    for (int a = tid; a < AA; a += 256) {
        float th = angles[a];
        s_cs[a] = make_float2(cosf(th) * inv_ds, sinf(th) * inv_ds);
    }
    __syncthreads();

    // Block tile 32x16; each thread does pixels ix0 and ix0+16.
    const int ix0 = blockIdx.x * 32 + threadIdx.x;
    const int iy  = blockIdx.y * 16 + threadIdx.y;
    const int b   = blockIdx.z;

    const float vsx = vol_spacing[1];
    const float xw0 = vol_origin[1] + (float)ix0 * vsx;
    const float yw  = vol_origin[0] + (float)iy * vol_spacing[0];
    const float off = -det_origin[0] * inv_ds;
    const float step_scale = 16.0f * vsx;   // u-step between the 2 pixels

    const float* __restrict__ srow = sino + (size_t)b * (AA * DD);

    float acc0 = 0.f, acc1 = 0.f;

    #pragma unroll 4
    for (int a = 0; a < AA; ++a) {
        const float2 cs = s_cs[a];
        const float u0 = fmaf(xw0, cs.x, fmaf(yw, cs.y, off));
        const float u1 = fmaf(cs.x, step_scale, u0);

        // Geometry keeps u in (2.7, 725.3) for this problem, so trunc==floor
        // and both taps are in-bounds; clamp is memory-safety only.
        {
            int   i  = (int)u0;
            i        = min(max(i, 0), DD - 2);
            float fr = u0 - (float)i;
            float v0 = srow[i];
            float v1 = srow[i + 1];
            acc0 = fmaf(fr, v1 - v0, acc0 + v0);
        }
        {
            int   i  = (int)u1;
            i        = min(max(i, 0), DD - 2);
            float fr = u1 - (float)i;
            float v0 = srow[i];
            float v1 = srow[i + 1];
            acc1 = fmaf(fr, v1 - v0, acc1 + v0);
        }
        srow += DD;
    }

    const size_t o = ((size_t)b * HH + iy) * WW + ix0;
    out[o]      = acc0;
    out[o + 16] = acc1;
}

extern "C" void kernel_launch(void* const* d_in, const int* in_sizes, int n_in,
                              void* d_out, int out_size, void* d_ws, size_t ws_size,
                              hipStream_t stream) {
    const float* sino        = (const float*)d_in[0];
    // d_in[1] = volume_shape (int64) — compile-time constants HH/WW used.
    const float* vol_origin  = (const float*)d_in[2];
    const float* det_origin  = (const float*)d_in[3];
    const float* vol_spacing = (const float*)d_in[4];
    const float* det_spacing = (const float*)d_in[5];
    const float* angles      = (const float*)d_in[6];
    float* out = (float*)d_out;

    dim3 block(16, 16, 1);
    dim3 grid(WW / 32, HH / 16, BB);
    bp_kernel<<<grid, block, 0, stream>>>(sino, vol_origin, det_origin,
                                          vol_spacing, det_spacing, angles, out);
}